// Round 21
// baseline (29.432 us; speedup 1.0000x reference)
//
#include <hip/hip_runtime.h>

typedef unsigned long long u64;
typedef unsigned int u32;

#define NB 64      // graphs
#define NN 128     // nodes per graph
#define NITER 5
#define NGEN 6     // initial labels + 5 WL iterations
#define SALT 0xD1B54A32D192ED03ULL
#define NPAIR_OFF (NB*(NB-1)/2)  // 2016 strict lower pairs
#define TSLOTS 256

__device__ __forceinline__ u64 mix64(u64 x) {
    u64 z = x + 0x9E3779B97F4A7C15ULL;
    z = (z ^ (z >> 30)) * 0xBF58476D1CE4E5B9ULL;
    z = (z ^ (z >> 27)) * 0x94D049BB133111EBULL;
    return z ^ (z >> 31);
}

// K0: adjacency pack, COALESCED + WIDE. 256 blocks x 256 threads (1/CU).
// Block (b, g): wave w packs rows g*32 + w*8 .. +7. Per row: two coalesced
// 256B loads + two ballots (pipelined across the 8-row unroll). Masks land
// in packed[q][b][u] so the chain kernel reads its quarter with ONE
// perfectly-coalesced 4B load. (R16's ballot regression was ballot inside
// the 64-block chain kernel; at 256 blocks the latency hides.)
__global__ __launch_bounds__(256) void wl_pack(const float* __restrict__ adj,
                                               u32* __restrict__ packed) {
    const int blk = blockIdx.x;
    const int b = blk >> 2;
    const int g = blk & 3;
    const int wv = threadIdx.x >> 6;
    const int lane = threadIdx.x & 63;
    const int r0 = g * 32 + wv * 8;
    const float* abase = adj + (size_t)b * NN * NN;
    #pragma unroll
    for (int k = 0; k < 8; ++k) {
        const int r = r0 + k;
        const float* arow = abase + (size_t)r * NN;
        const u64 m0 = __ballot(arow[lane] > 0.5f);
        const u64 m1 = __ballot(arow[64 + lane] > 0.5f);
        if (lane < 4) {   // masks are wave-uniform; lanes 0..3 store quarters
            const u64 src = (lane < 2) ? m0 : m1;
            const u32 qv = (lane & 1) ? (u32)(src >> 32) : (u32)src;
            packed[lane * (NB * NN) + b * NN + r] = qv;
        }
    }
}

// K1: per-graph WL chain. 64 blocks x 512 threads = 4 quarter-threads/node.
// Quarter-mask comes from packed[] via one coalesced 4B load (the uncoalesced
// float4 pack was the prime suspect for W1 ~ 18us). Exports u32 labels.
__global__ __launch_bounds__(512) void wl_iter(const u32* __restrict__ packed,
                                               const int* __restrict__ labels,
                                               u32* __restrict__ hgen32,
                                               float* __restrict__ out) {
    const int b = blockIdx.x;
    const int t = threadIdx.x;
    const int u = t & 127;   // node
    const int q = t >> 7;    // quarter 0..3

    __shared__ u64 gsh[NN];
    __shared__ u64 psum[3][NN];

    const u32 m = packed[q * (NB * NN) + b * NN + u];   // coalesced

    u64 h = 0;
    if (q == 0) {
        h = mix64((u64)(u32)labels[b * NN + u]);
        hgen32[(size_t)b * (NGEN * NN) + u] = (u32)h;   // generation 0
        if (u == 0) out[b * NB + b] = 1.0f;
    }

    for (int it = 0; it < NITER; ++it) {
        if (q == 0) gsh[u] = mix64(h ^ SALT);
        __syncthreads();
        u64 s = 0;
        {
            u32 mm = m;
            const u64* gp = gsh + q * 32;
            while (mm) { int j = __builtin_ctz(mm); mm &= mm - 1; s += gp[j]; }
        }
        if (q) psum[q - 1][u] = s;
        __syncthreads();
        if (q == 0) {
            h = mix64(mix64(h) + s + psum[0][u] + psum[1][u] + psum[2][u]);
            hgen32[(size_t)b * (NGEN * NN) + (it + 1) * NN + u] = (u32)h;
        }
    }
}

// K2 (R20 verbatim): per-(graph,gen) compact table — 384 blocks x 128 thr.
__global__ __launch_bounds__(128) void wl_tables(const u32* __restrict__ hgen32,
                                                 uint2* __restrict__ tabg,
                                                 float* __restrict__ Kpart) {
    const int bg = blockIdx.x;   // b*NGEN + gen
    const int t = threadIdx.x;

    __shared__ u32 keys[TSLOTS];
    __shared__ u32 cnts[TSLOTS];
    keys[t] = 0u; keys[t + 128] = 0u;
    cnts[t] = 0u; cnts[t + 128] = 0u;
    __syncthreads();

    const u32 h = hgen32[(size_t)bg * NN + t];
    u32 s = h & (TSLOTS - 1);
    for (;;) {
        u32 old = atomicCAS(&keys[s], 0u, h);
        if (old == 0u || old == h) { atomicAdd(&cnts[s], 1u); break; }
        s = (s + 1) & (TSLOTS - 1);
    }
    __syncthreads();

    u32 acc = 0;
    #pragma unroll
    for (int k = 0; k < 2; ++k) {
        const int idx = t + 128 * k;
        const u32 kk = keys[idx];
        const u32 cc = cnts[idx];
        tabg[(size_t)bg * TSLOTS + idx] = make_uint2(kk, cc);
        acc += cc * cc;
    }
    #pragma unroll
    for (int off = 32; off > 0; off >>= 1) acc += __shfl_down(acc, off);
    __shared__ u32 part[2];
    if ((t & 63) == 0) part[t >> 6] = acc;
    __syncthreads();
    if (t == 0) Kpart[bg] = (float)(part[0] + part[1]);
}

// K3 (R20 verbatim): one block per strict lower pair, 256 threads.
__global__ __launch_bounds__(256) void wl_pairs(const u32* __restrict__ hgen32,
                                                const uint2* __restrict__ tabg,
                                                const float* __restrict__ Kpart,
                                                float* __restrict__ out) {
    const int p = blockIdx.x;
    int b1 = (int)((1.0f + sqrtf(1.0f + 8.0f * (float)p)) * 0.5f);
    while (b1 * (b1 - 1) / 2 > p) --b1;
    while ((b1 + 1) * b1 / 2 <= p) ++b1;
    const int b2 = p - b1 * (b1 - 1) / 2;

    const int t = threadIdx.x;
    __shared__ uint2 tab[NGEN * TSLOTS];  // 12 KiB
    __shared__ u32 red[4];
    __shared__ float dred[2 * NGEN];

    if (t < 2 * NGEN)
        dred[t] = Kpart[(t < NGEN ? b1 : b2) * NGEN + (t % NGEN)];

    {   // stage b2's tables: 1536 uint2 = 768 uint4 over 256 threads
        const uint4* src = (const uint4*)(tabg + (size_t)b2 * NGEN * TSLOTS);
        uint4* dst = (uint4*)tab;
        #pragma unroll
        for (int k = 0; k < 3; ++k) dst[t + 256 * k] = src[t + 256 * k];
    }
    __syncthreads();

    u32 c = 0;
    const u32* la = hgen32 + (size_t)b1 * (NGEN * NN);
    #pragma unroll
    for (int k = 0; k < 3; ++k) {
        const int idx = t + 256 * k;        // 0..767 -> gen = idx>>7
        const u32 a = la[idx];
        const int base = (idx >> 7) * TSLOTS;
        u32 s = a & (TSLOTS - 1);
        for (;;) {
            const uint2 kv = tab[base + s];
            if (kv.x == a) { c += kv.y; break; }
            if (kv.x == 0u) break;
            s = (s + 1) & (TSLOTS - 1);
        }
    }

    #pragma unroll
    for (int off = 32; off > 0; off >>= 1) c += __shfl_down(c, off);
    if ((t & 63) == 0) red[t >> 6] = c;
    __syncthreads();
    if (t == 0) {
        float d1 = 0.f, d2 = 0.f;
        #pragma unroll
        for (int g = 0; g < NGEN; ++g) { d1 += dred[g]; d2 += dred[NGEN + g]; }
        const float v = (float)(red[0] + red[1] + red[2] + red[3])
                      / (sqrtf(d1) * sqrtf(d2));
        out[b1 * NB + b2] = v;
        out[b2 * NB + b1] = v;
    }
}

extern "C" void kernel_launch(void* const* d_in, const int* in_sizes, int n_in,
                              void* d_out, int out_size, void* d_ws, size_t ws_size,
                              hipStream_t stream) {
    const float* adj   = (const float*)d_in[0];   // [64,128,128] fp32 (0/1)
    const int*  labels = (const int*)d_in[1];     // [64,128] int32
    float* out = (float*)d_out;                   // [64,64] fp32

    char* ws = (char*)d_ws;
    u32*   hgen32 = (u32*)ws;                      // 64*768*4  = 192 KiB
    u32*   packed = (u32*)(ws + 192 * 1024);       // 4*8192*4  = 128 KiB
    uint2* tabg   = (uint2*)(ws + 512 * 1024);     // 384*256*8 = 768 KiB
    float* Kpart  = (float*)(ws + 1536 * 1024);    // 1.5 KiB

    wl_pack  <<<NB * 4, 256, 0, stream>>>(adj, packed);
    wl_iter  <<<NB, 512, 0, stream>>>(packed, labels, hgen32, out);
    wl_tables<<<NB * NGEN, 128, 0, stream>>>(hgen32, tabg, Kpart);
    wl_pairs <<<NPAIR_OFF, 256, 0, stream>>>(hgen32, tabg, Kpart, out);
}